// Round 4
// baseline (22082.207 us; speedup 1.0000x reference)
//
#include <hip/hip_runtime.h>
#include <hip/hip_bf16.h>

#define T_SEQ 512
#define BATCH 256
#define HID   1024
#define EMBD  256
#define NCLS  10

typedef __bf16 bf16x8 __attribute__((ext_vector_type(8)));
typedef float  floatx16 __attribute__((ext_vector_type(16)));
typedef float  floatx2 __attribute__((ext_vector_type(2)));
typedef unsigned short ushortx8 __attribute__((ext_vector_type(8)));

__device__ __forceinline__ unsigned int f2bf(float f) {
    unsigned int u = __builtin_bit_cast(unsigned int, f);
    u += 0x7fffu + ((u >> 16) & 1u);
    return u >> 16;
}
__device__ __forceinline__ float sig_fast(float x) {
    return __builtin_amdgcn_rcpf(1.0f + __expf(-x));
}
__device__ __forceinline__ float tanh_fast(float x) {
    return 1.0f - 2.0f * __builtin_amdgcn_rcpf(1.0f + __expf(2.0f * x));
}

// -------------------- prep: XW[tok][gate][n] = emb[tok] @ Wx_gate + b_gate ---
__global__ void prep_xw_kernel(const float* __restrict__ emb,
                               const float* __restrict__ wgx, const float* __restrict__ wix,
                               const float* __restrict__ wfx, const float* __restrict__ wox,
                               const float* __restrict__ bg,  const float* __restrict__ bi,
                               const float* __restrict__ bf,  const float* __restrict__ bo,
                               float* __restrict__ XW) {
    int gid = blockIdx.x * blockDim.x + threadIdx.x;     // 3*4*1024 = 12288
    if (gid >= 3 * 4 * HID) return;
    int tok  = gid >> 12;
    int gate = (gid >> 10) & 3;
    int n    = gid & 1023;
    const float* W = gate == 0 ? wgx : gate == 1 ? wix : gate == 2 ? wfx : wox;
    const float* B = gate == 0 ? bg  : gate == 1 ? bi  : gate == 2 ? bf  : bo;
    float acc = B[n];
    const float* e = emb + tok * EMBD;
    for (int k = 0; k < EMBD; ++k) acc += e[k] * W[k * HID + n];
    XW[gid] = acc;
}

// ---- prep: Wt in 32x32x16 MFMA B-fragment order (R0 layout) ----
// frag = ((w*4+g)*2+kh)*32 + i ; Wt[frag*512 + lane*8 + e]
//   = bf16( W_g[k = kh*512 + i*16 + (lane>>5)*8 + e][j = w*32 + (lane&31)] )
__global__ void prep_w_kernel(const float* __restrict__ wgh, const float* __restrict__ wih,
                              const float* __restrict__ wfh, const float* __restrict__ woh,
                              unsigned short* __restrict__ Wt) {
    int bid = blockIdx.x;                 // 8192 = g(4) x kh(2) x i(32) x w(32)
    int w   = bid & 31;
    int i   = (bid >> 5) & 31;
    int kh  = (bid >> 10) & 1;
    int g   = bid >> 11;
    const float* W = g == 0 ? wgh : g == 1 ? wih : g == 2 ? wfh : woh;
    int lane = threadIdx.x;               // 64
    int j    = w * 32 + (lane & 31);
    int k0   = kh * 512 + i * 16 + (lane >> 5) * 8;
    ushortx8 o8;
    #pragma unroll
    for (int e = 0; e < 8; ++e) o8[e] = (unsigned short)f2bf(W[(k0 + e) * HID + j]);
    int frag = ((w * 4 + g) * 2 + kh) * 32 + i;
    *(ushortx8*)&Wt[frag * 512 + lane * 8] = o8;
}

// -------------------- persistent recurrent kernel ---------------------------
// 256 WGs x 512 threads. grp = blockIdx%8 owns 32 batch rows; w = blockIdx/8
// owns 32 hidden cols. Wave wv: gate gv = wv>>1, K-half kh = wv&1 (R0-proven
// math structure: 8 partial tiles, 2-term GSUM).
//
// R10: half-granular pipelined front-end (R9 showed GEMM phase is already
// MFMA-issue-saturated; the cost is the serial spin/stage/barrier chain —
// 62% of cycles issue nothing).
//  - per-half flag wait: wave (g,kh) polls only its 16 producers (cols of
//    half kh), with an acquire fence after the spin (old ordering barrier
//    is gone).
//  - per-wave staging: wave (g,kh) stages rows g*8..g*8+8 of half kh
//    (16 qword agent-scope loads/lane), then release-increments LDS counter
//    scnt[kh]; waves of half kh poll scnt[kh] >= 4*(s+1) (monotone) instead
//    of a whole-WG barrier. A half's GEMM starts as soon as its own 32 KB
//    lands; producer skew is absorbed per-half.
//  - per-wave early publish: after its own ew h-stores each wave
//    release-fetch_adds flags[w] (consumer target 8*s) — publication no
//    longer waits for an end-of-step barrier; store drain is per-wave.
//  - barriers per step: 4 -> 2 (scatter->ew;  ew->next scatter/stage, which
//    orders gbuf and hs reuse across steps).
// h exchange scopes unchanged from R7 (workgroup-scope stores into shared
// XCD L2 when co-XCD, system-scope fallback; agent-scope sc0 loads).
__global__ __launch_bounds__(512, 2)
void lstm_kernel(const int* __restrict__ x, const float* __restrict__ XW,
                 const unsigned short* __restrict__ Wt,
                 unsigned int* __restrict__ hbuf32, int* __restrict__ flags,
                 int* __restrict__ xflag) {
    __shared__ unsigned short hs[32 * 1032];      // h stage, +8 shorts pad (66048 B)
    __shared__ float gbuf[8 * 32 * 36];           // [gate][kh][row][col+pad] (36864 B)
    __shared__ float xwl[384];                    // [tok][gate][32 cols]     (1536 B)
    __shared__ unsigned char xtok[32 * 512];      // tokens, byte-packed      (16384 B)
    __shared__ int scnt[2];                       // per-half stage counters (monotone)
    __shared__ int use_local_sh;

    const int tid  = threadIdx.x;
    const int grp  = blockIdx.x & 7;
    const int w    = blockIdx.x >> 3;
    const int wv   = tid >> 6;
    const int gv   = wv >> 1;                  // gate
    const int kh   = wv & 1;                   // K-half
    const int lane = tid & 63;
    const int m32  = lane & 31;
    const int hv5  = lane >> 5;

    // ---- XCD-locality check (one-time, system-scope => placement-safe) ----
    {
        int xcc = 0;
        asm volatile("s_getreg_b32 %0, hwreg(HW_REG_XCC_ID)" : "=s"(xcc));
        if (tid == 0) {
            __hip_atomic_store(&xflag[grp * 32 + w], xcc + 1, __ATOMIC_RELAXED,
                               __HIP_MEMORY_SCOPE_SYSTEM);
        }
        if (wv == 0) {
            int v;
            for (;;) {
                v = __hip_atomic_load(&xflag[grp * 32 + (lane & 31)], __ATOMIC_RELAXED,
                                      __HIP_MEMORY_SCOPE_SYSTEM);
                if (__all(v != 0)) break;
                __builtin_amdgcn_s_sleep(2);
            }
            int v0 = __shfl(v, 0, 64);
            if (lane == 0) use_local_sh = __all(v == v0) ? 1 : 0;
        }
    }

    // one-time: B fragments into registers (128 regs/lane, AGPR-backed)
    bf16x8 Bf[32];
    {
        const unsigned short* wb = Wt + (size_t)(((w * 4 + gv) * 2 + kh) * 32) * 512
                                      + (size_t)lane * 8;
        #pragma unroll
        for (int i = 0; i < 32; ++i)
            Bf[i] = *(const bf16x8*)(wb + i * 512);
    }
    // one-time: XW slice into LDS
    if (tid < 384) {
        int tok = tid >> 7, g = (tid >> 5) & 3, jl = tid & 31;
        xwl[tid] = XW[(tok * 4 + g) * HID + w * 32 + jl];
    }
    if (tid < 2) scnt[tid] = 0;
    // one-time: token table into LDS (byte-packed)
    #pragma unroll
    for (int it = 0; it < 32; ++it) {
        int flat = it * 512 + tid;                 // 16384 tokens
        int row  = flat >> 9;
        int col  = flat & 511;
        xtok[flat] = (unsigned char)x[(grp * 32 + row) * T_SEQ + col];
    }
    __syncthreads();
    const bool use_local = (use_local_sh != 0);

    // elementwise ownership: thread -> row = tid>>4, cols jc2*2..+2
    const int erow = tid >> 4;
    const int jc2  = tid & 15;
    float cst[2] = {0.f, 0.f};
    unsigned long long* hs64 = (unsigned long long*)hs;

    for (int s = 0; s < T_SEQ; ++s) {
        // ---- per-half wait: half kh needs producers w' in [kh*16, kh*16+16) ----
        if (s > 0) {
            const int target = 8 * s;          // 8 wave-publishes per producer per step
            const int fidx = grp * 32 + kh * 16 + (lane & 15);
            if (use_local) {
                for (;;) {
                    int v = (lane < 16)
                        ? __hip_atomic_load(&flags[fidx], __ATOMIC_RELAXED,
                                            __HIP_MEMORY_SCOPE_AGENT)
                        : 0x7fffffff;
                    if (__all(v >= target)) break;
                    __builtin_amdgcn_s_sleep(1);
                }
                __builtin_amdgcn_fence(__ATOMIC_ACQUIRE, "agent");
            } else {
                for (;;) {
                    int v = (lane < 16)
                        ? __hip_atomic_load(&flags[fidx], __ATOMIC_RELAXED,
                                            __HIP_MEMORY_SCOPE_SYSTEM)
                        : 0x7fffffff;
                    if (__all(v >= target)) break;
                    __builtin_amdgcn_s_sleep(1);
                }
                __builtin_amdgcn_fence(__ATOMIC_ACQUIRE, "");
            }
        }

        // ---- per-wave stage: rows gv*8..+8 of half kh (8 rows x 128 qwords) ----
        {
            const unsigned long long* hp64 = (const unsigned long long*)
                (hbuf32 + (size_t)(s & 1) * (BATCH * HID / 2)) + (size_t)grp * 32 * 256;
            unsigned long long tmp[16];
            if (use_local) {
                #pragma unroll
                for (int it = 0; it < 16; ++it) {
                    int flat = it * 64 + lane;           // 0..1023
                    int row  = gv * 8 + (flat >> 7);
                    int colq = kh * 128 + (flat & 127);
                    tmp[it] = __hip_atomic_load(&hp64[row * 256 + colq],
                                                __ATOMIC_RELAXED, __HIP_MEMORY_SCOPE_AGENT);
                }
            } else {
                #pragma unroll
                for (int it = 0; it < 16; ++it) {
                    int flat = it * 64 + lane;
                    int row  = gv * 8 + (flat >> 7);
                    int colq = kh * 128 + (flat & 127);
                    tmp[it] = __hip_atomic_load(&hp64[row * 256 + colq],
                                                __ATOMIC_RELAXED, __HIP_MEMORY_SCOPE_SYSTEM);
                }
            }
            #pragma unroll
            for (int it = 0; it < 16; ++it) {
                int flat = it * 64 + lane;
                int row  = gv * 8 + (flat >> 7);
                int colq = kh * 128 + (flat & 127);
                hs64[row * 258 + colq] = tmp[it];
            }
            if (lane == 0)
                __hip_atomic_fetch_add(&scnt[kh], 1, __ATOMIC_RELEASE,
                                       __HIP_MEMORY_SCOPE_WORKGROUP);
        }
        // ---- wait for my half fully staged (4 waves, monotone target) ----
        {
            const int starget = 4 * (s + 1);
            for (;;) {
                int v = __hip_atomic_load(&scnt[kh], __ATOMIC_RELAXED,
                                          __HIP_MEMORY_SCOPE_WORKGROUP);
                if (v >= starget) break;
            }
            __builtin_amdgcn_fence(__ATOMIC_ACQUIRE, "workgroup");
        }

        // ---- GEMM: 32x32 tile for gate gv over K-half kh, B from registers ----
        floatx16 acc = {0.f,0.f,0.f,0.f,0.f,0.f,0.f,0.f,0.f,0.f,0.f,0.f,0.f,0.f,0.f,0.f};
        const unsigned short* ap = hs + m32 * 1032 + kh * 512 + hv5 * 8;
        #pragma unroll
        for (int i = 0; i < 32; ++i) {
            bf16x8 a = *(const bf16x8*)(ap + i * 16);
            acc = __builtin_amdgcn_mfma_f32_32x32x16_bf16(a, Bf[i], acc, 0, 0, 0);
        }

        // ---- scatter C (col=lane&31, row=(reg&3)+8*(reg>>2)+4*(lane>>5)) ----
        {
            float* gb = &gbuf[(size_t)(gv * 2 + kh) * 32 * 36];
            #pragma unroll
            for (int reg = 0; reg < 16; ++reg) {
                int row = (reg & 3) + 8 * (reg >> 2) + 4 * hv5;
                gb[row * 36 + m32] = acc[reg];
            }
        }
        __syncthreads();                       // barrier b: gbuf complete

        // ---- elementwise LSTM cell update, h(s+1) out ----
        {
            int tk = xtok[erow * 512 + s];
            const float* xb = &xwl[tk * 128];
            const int go = erow * 36 + jc2 * 2;
            floatx2 ag = *(const floatx2*)&gbuf[0 * 32 * 36 + go]
                       + *(const floatx2*)&gbuf[1 * 32 * 36 + go];
            floatx2 ai = *(const floatx2*)&gbuf[2 * 32 * 36 + go]
                       + *(const floatx2*)&gbuf[3 * 32 * 36 + go];
            floatx2 af = *(const floatx2*)&gbuf[4 * 32 * 36 + go]
                       + *(const floatx2*)&gbuf[5 * 32 * 36 + go];
            floatx2 ao = *(const floatx2*)&gbuf[6 * 32 * 36 + go]
                       + *(const floatx2*)&gbuf[7 * 32 * 36 + go];
            floatx2 xg = *(const floatx2*)&xb[0 * 32 + jc2 * 2];
            floatx2 xi = *(const floatx2*)&xb[1 * 32 + jc2 * 2];
            floatx2 xf = *(const floatx2*)&xb[2 * 32 + jc2 * 2];
            floatx2 xo = *(const floatx2*)&xb[3 * 32 + jc2 * 2];
            unsigned int hvv[2];
            #pragma unroll
            for (int u = 0; u < 2; ++u) {
                float g  = tanh_fast(ag[u] + xg[u]);
                float ii = sig_fast(ai[u] + xi[u]);
                float ff = sig_fast(af[u] + xf[u]);
                float oo = sig_fast(ao[u] + xo[u]);
                float cn = g * ii + cst[u] * ff;
                float h  = tanh_fast(cn) * oo;
                cst[u]   = (tk != 0) ? cn : 0.0f;   // pad = ((x+1)//2) in {0,1,1}
                hvv[u]   = f2bf(h);
            }
            unsigned int* hnext = hbuf32 + (size_t)((s + 1) & 1) * (BATCH * HID / 2);
            unsigned int* hp = &hnext[((grp * 32 + erow) * HID + w * 32 + jc2 * 2) >> 1];
            unsigned int hval = hvv[0] | (hvv[1] << 16);
            if (use_local) {
                // plain write-back store into the shared XCD L2 (no LLC RTT)
                __hip_atomic_store(hp, hval, __ATOMIC_RELAXED, __HIP_MEMORY_SCOPE_WORKGROUP);
            } else {
                __hip_atomic_store(hp, hval, __ATOMIC_RELAXED, __HIP_MEMORY_SCOPE_SYSTEM);
            }
        }

        // ---- per-wave early publish: release orders this wave's h stores ----
        if (s < T_SEQ - 1 && lane == 0) {
            if (use_local) {
                __hip_atomic_fetch_add(&flags[grp * 32 + w], 1, __ATOMIC_RELEASE,
                                       __HIP_MEMORY_SCOPE_AGENT);
            } else {
                __hip_atomic_fetch_add(&flags[grp * 32 + w], 1, __ATOMIC_RELEASE,
                                       __HIP_MEMORY_SCOPE_SYSTEM);
            }
        }
        __syncthreads();                       // barrier d: gbuf/hs reuse ordering
    }
}

// -------------------- projection + log_softmax over batch dim ---------------
__global__ void proj_kernel(const unsigned short* __restrict__ h,
                            const float* __restrict__ wph, const float* __restrict__ bp,
                            float* __restrict__ out) {
    __shared__ float wl[HID * NCLS];
    __shared__ float red[256];
    int tid = threadIdx.x;      // = batch row
    for (int i = tid; i < HID * NCLS; i += 256) wl[i] = wph[i];
    __syncthreads();
    float p[NCLS];
    #pragma unroll
    for (int c2 = 0; c2 < NCLS; ++c2) p[c2] = bp[c2];
    const unsigned short* hr = h + tid * HID;
    for (int k0 = 0; k0 < HID / 8; ++k0) {
        bf16x8 hv = *(const bf16x8*)(hr + k0 * 8);
        #pragma unroll
        for (int j = 0; j < 8; ++j) {
            float hk = (float)hv[j];
            #pragma unroll
            for (int c2 = 0; c2 < NCLS; ++c2) p[c2] += hk * wl[(k0 * 8 + j) * NCLS + c2];
        }
    }
    for (int c2 = 0; c2 < NCLS; ++c2) {
        red[tid] = p[c2];
        __syncthreads();
        for (int s = 128; s > 0; s >>= 1) {
            if (tid < s) red[tid] = fmaxf(red[tid], red[tid + s]);
            __syncthreads();
        }
        float mx = red[0];
        __syncthreads();
        red[tid] = __expf(p[c2] - mx);
        __syncthreads();
        for (int s = 128; s > 0; s >>= 1) {
            if (tid < s) red[tid] += red[tid + s];
            __syncthreads();
        }
        float lse = mx + __logf(red[0]);
        __syncthreads();
        out[tid * NCLS + c2] = p[c2] - lse;
    }
}

// ----------------------------------------------------------------------------
extern "C" void kernel_launch(void* const* d_in, const int* in_sizes, int n_in,
                              void* d_out, int out_size, void* d_ws, size_t ws_size,
                              hipStream_t stream) {
    const int*   x    = (const int*)d_in[0];
    const float* emb  = (const float*)d_in[1];
    const float* wgx  = (const float*)d_in[2];
    const float* wgh  = (const float*)d_in[3];
    const float* bg_  = (const float*)d_in[4];
    const float* wix  = (const float*)d_in[5];
    const float* wih  = (const float*)d_in[6];
    const float* bi_  = (const float*)d_in[7];
    const float* wfx  = (const float*)d_in[8];
    const float* wfh  = (const float*)d_in[9];
    const float* bf_  = (const float*)d_in[10];
    const float* wox  = (const float*)d_in[11];
    const float* woh  = (const float*)d_in[12];
    const float* bo_  = (const float*)d_in[13];
    const float* wph  = (const float*)d_in[14];
    const float* bp_  = (const float*)d_in[15];
    float* out = (float*)d_out;

    char* wsp = (char*)d_ws;
    int*            flags = (int*)wsp;                                      // 4 KB
    int*            xflag = (int*)(wsp + 4096);                             // 4 KB
    float*          XW    = (float*)(wsp + 8192);                           // 48 KB
    unsigned short* Wt    = (unsigned short*)(wsp + 8192 + 49152);          // 8 MB
    unsigned int*   hbuf32= (unsigned int*)(wsp + 8192 + 49152 + 8388608);  // 1 MB

    hipMemsetAsync(flags, 0, 8192, stream);                                  // flags+xflag
    hipMemsetAsync(hbuf32, 0, BATCH * HID * sizeof(unsigned short), stream); // h0 = 0

    prep_xw_kernel<<<48, 256, 0, stream>>>(emb, wgx, wix, wfx, wox,
                                           bg_, bi_, bf_, bo_, XW);
    prep_w_kernel<<<8192, 64, 0, stream>>>(wgh, wih, wfh, woh, Wt);

    void* args[] = { (void*)&x, (void*)&XW, (void*)&Wt, (void*)&hbuf32,
                     (void*)&flags, (void*)&xflag };
    hipError_t cerr = hipLaunchCooperativeKernel((void*)lstm_kernel, dim3(256), dim3(512),
                                                 args, 0, stream);
    if (cerr != hipSuccess) {
        // Fallback: plain launch. The flag protocol needs only co-residency,
        // which grid=256 at 1 WG/CU provides.
        lstm_kernel<<<dim3(256), dim3(512), 0, stream>>>(x, XW, Wt, hbuf32, flags, xflag);
    }

    proj_kernel<<<1, 256, 0, stream>>>((const unsigned short*)hbuf32, wph, bp_, out);
}

// Round 5
// 3300.007 us; speedup vs baseline: 6.6916x; 6.6916x over previous
//
#include <hip/hip_runtime.h>
#include <hip/hip_bf16.h>

#define T_SEQ 512
#define BATCH 256
#define HID   1024
#define EMBD  256
#define NCLS  10

typedef __bf16 bf16x8 __attribute__((ext_vector_type(8)));
typedef float  floatx16 __attribute__((ext_vector_type(16)));
typedef float  floatx2 __attribute__((ext_vector_type(2)));
typedef unsigned short ushortx8 __attribute__((ext_vector_type(8)));

__device__ __forceinline__ unsigned int f2bf(float f) {
    unsigned int u = __builtin_bit_cast(unsigned int, f);
    u += 0x7fffu + ((u >> 16) & 1u);
    return u >> 16;
}
__device__ __forceinline__ float sig_fast(float x) {
    return __builtin_amdgcn_rcpf(1.0f + __expf(-x));
}
__device__ __forceinline__ float tanh_fast(float x) {
    return 1.0f - 2.0f * __builtin_amdgcn_rcpf(1.0f + __expf(2.0f * x));
}

// -------------------- prep: XW[tok][gate][n] = emb[tok] @ Wx_gate + b_gate ---
__global__ void prep_xw_kernel(const float* __restrict__ emb,
                               const float* __restrict__ wgx, const float* __restrict__ wix,
                               const float* __restrict__ wfx, const float* __restrict__ wox,
                               const float* __restrict__ bg,  const float* __restrict__ bi,
                               const float* __restrict__ bf,  const float* __restrict__ bo,
                               float* __restrict__ XW) {
    int gid = blockIdx.x * blockDim.x + threadIdx.x;     // 3*4*1024 = 12288
    if (gid >= 3 * 4 * HID) return;
    int tok  = gid >> 12;
    int gate = (gid >> 10) & 3;
    int n    = gid & 1023;
    const float* W = gate == 0 ? wgx : gate == 1 ? wix : gate == 2 ? wfx : wox;
    const float* B = gate == 0 ? bg  : gate == 1 ? bi  : gate == 2 ? bf  : bo;
    float acc = B[n];
    const float* e = emb + tok * EMBD;
    for (int k = 0; k < EMBD; ++k) acc += e[k] * W[k * HID + n];
    XW[gid] = acc;
}

// ---- prep: Wt in 32x32x16 MFMA B-fragment order (R0 layout) ----
// frag = ((w*4+g)*2+kh)*32 + i ; Wt[frag*512 + lane*8 + e]
//   = bf16( W_g[k = kh*512 + i*16 + (lane>>5)*8 + e][j = w*32 + (lane&31)] )
__global__ void prep_w_kernel(const float* __restrict__ wgh, const float* __restrict__ wih,
                              const float* __restrict__ wfh, const float* __restrict__ woh,
                              unsigned short* __restrict__ Wt) {
    int bid = blockIdx.x;                 // 8192 = g(4) x kh(2) x i(32) x w(32)
    int w   = bid & 31;
    int i   = (bid >> 5) & 31;
    int kh  = (bid >> 10) & 1;
    int g   = bid >> 11;
    const float* W = g == 0 ? wgh : g == 1 ? wih : g == 2 ? wfh : woh;
    int lane = threadIdx.x;               // 64
    int j    = w * 32 + (lane & 31);
    int k0   = kh * 512 + i * 16 + (lane >> 5) * 8;
    ushortx8 o8;
    #pragma unroll
    for (int e = 0; e < 8; ++e) o8[e] = (unsigned short)f2bf(W[(k0 + e) * HID + j]);
    int frag = ((w * 4 + g) * 2 + kh) * 32 + i;
    *(ushortx8*)&Wt[frag * 512 + lane * 8] = o8;
}

// -------------------- persistent recurrent kernel ---------------------------
// 256 WGs x 512 threads. grp = blockIdx%8 owns 32 batch rows; w = blockIdx/8
// owns 32 hidden cols. Wave wv: gate gv = wv>>1, K-half kh = wv&1 (R0-proven
// math structure: 8 partial tiles, 2-term GSUM, single acc).
//
// R11: half-granular pipeline, FENCE-FREE. R10 post-mortem: agent-scope
// acquire/release fences inside the loop trigger per-step L2 invalidate/
// writeback on gfx950 (non-coherent per-XCD L2s) -> WRITE_SIZE 1MB->300MB,
// FETCH 34MB->111GB, 12x regression. NEVER use acquire/release at agent or
// system scope in the step loop. All ordering here is: wave-local
// s_waitcnt vmcnt drains + same-L2 visibility (R0's proven protocol), and
// workgroup-scope fences (s_waitcnt only, no cache ops) for LDS handoff.
//  - per-wave early publish: after own ew h-stores: s_waitcnt vmcnt(0),
//    then lane0 RELAXED fetch_add(&flags[w],1) at WORKGROUP scope (RMW
//    executes in the local XCD L2; single-WG writer per address; consumers
//    on same XCD read it with sc0 loads). SYSTEM scope in fallback.
//  - per-half spin: wave (gv,kh) polls its 16 producers to 8*s (monotone),
//    relaxed loads, compiler barrier after (no HW fence; R0 visibility
//    argument: flag and data live in the same L2, producer drained vmcnt
//    between data stores and flag RMW).
//  - per-wave staging of 8 rows x half kh; LDS counter scnt[kh] with
//    workgroup-scope release/acquire (s_waitcnt only). GEMM of a half
//    starts as soon as its 32 KB is staged.
//  - 2 barriers/step: scatter->ew, end-of-step (hs/gbuf WAR). Parity-2
//    safety unchanged: publish still at ew time, so no WG can overwrite
//    hbuf parity p while any peer still stages from it.
__global__ __launch_bounds__(512, 2)
void lstm_kernel(const int* __restrict__ x, const float* __restrict__ XW,
                 const unsigned short* __restrict__ Wt,
                 unsigned int* __restrict__ hbuf32, int* __restrict__ flags,
                 int* __restrict__ xflag) {
    __shared__ unsigned short hs[32 * 1032];      // h stage, +8 shorts pad (66048 B)
    __shared__ float gbuf[8 * 32 * 36];           // [gate][kh][row][col+pad] (36864 B)
    __shared__ float xwl[384];                    // [tok][gate][32 cols]     (1536 B)
    __shared__ unsigned char xtok[32 * 512];      // tokens, byte-packed      (16384 B)
    __shared__ int scnt[2];                       // per-half stage counters (monotone)
    __shared__ int use_local_sh;

    const int tid  = threadIdx.x;
    const int grp  = blockIdx.x & 7;
    const int w    = blockIdx.x >> 3;
    const int wv   = tid >> 6;
    const int gv   = wv >> 1;                  // gate
    const int kh   = wv & 1;                   // K-half
    const int lane = tid & 63;
    const int m32  = lane & 31;
    const int hv5  = lane >> 5;

    // ---- XCD-locality check (one-time, system-scope => placement-safe) ----
    {
        int xcc = 0;
        asm volatile("s_getreg_b32 %0, hwreg(HW_REG_XCC_ID)" : "=s"(xcc));
        if (tid == 0) {
            __hip_atomic_store(&xflag[grp * 32 + w], xcc + 1, __ATOMIC_RELAXED,
                               __HIP_MEMORY_SCOPE_SYSTEM);
        }
        if (wv == 0) {
            int v;
            for (;;) {
                v = __hip_atomic_load(&xflag[grp * 32 + (lane & 31)], __ATOMIC_RELAXED,
                                      __HIP_MEMORY_SCOPE_SYSTEM);
                if (__all(v != 0)) break;
                __builtin_amdgcn_s_sleep(2);
            }
            int v0 = __shfl(v, 0, 64);
            if (lane == 0) use_local_sh = __all(v == v0) ? 1 : 0;
        }
    }

    // one-time: B fragments into registers (128 regs/lane, AGPR-backed)
    bf16x8 Bf[32];
    {
        const unsigned short* wb = Wt + (size_t)(((w * 4 + gv) * 2 + kh) * 32) * 512
                                      + (size_t)lane * 8;
        #pragma unroll
        for (int i = 0; i < 32; ++i)
            Bf[i] = *(const bf16x8*)(wb + i * 512);
    }
    // one-time: XW slice into LDS
    if (tid < 384) {
        int tok = tid >> 7, g = (tid >> 5) & 3, jl = tid & 31;
        xwl[tid] = XW[(tok * 4 + g) * HID + w * 32 + jl];
    }
    if (tid < 2) scnt[tid] = 0;
    // one-time: token table into LDS (byte-packed)
    #pragma unroll
    for (int it = 0; it < 32; ++it) {
        int flat = it * 512 + tid;                 // 16384 tokens
        int row  = flat >> 9;
        int col  = flat & 511;
        xtok[flat] = (unsigned char)x[(grp * 32 + row) * T_SEQ + col];
    }
    __syncthreads();
    const bool use_local = (use_local_sh != 0);

    // elementwise ownership: thread -> row = tid>>4, cols jc2*2..+2
    const int erow = tid >> 4;
    const int jc2  = tid & 15;
    float cst[2] = {0.f, 0.f};
    unsigned long long* hs64 = (unsigned long long*)hs;

    for (int s = 0; s < T_SEQ; ++s) {
        // ---- per-half wait: half kh needs producers w' in [kh*16, kh*16+16) ----
        if (s > 0) {
            const int target = 8 * s;          // 8 wave-publishes per producer per step
            const int fidx = grp * 32 + kh * 16 + (lane & 15);
            if (use_local) {
                for (;;) {
                    int v = (lane < 16)
                        ? __hip_atomic_load(&flags[fidx], __ATOMIC_RELAXED,
                                            __HIP_MEMORY_SCOPE_AGENT)
                        : 0x7fffffff;
                    if (__all(v >= target)) break;
                    __builtin_amdgcn_s_sleep(1);
                }
            } else {
                for (;;) {
                    int v = (lane < 16)
                        ? __hip_atomic_load(&flags[fidx], __ATOMIC_RELAXED,
                                            __HIP_MEMORY_SCOPE_SYSTEM)
                        : 0x7fffffff;
                    if (__all(v >= target)) break;
                    __builtin_amdgcn_s_sleep(1);
                }
            }
            asm volatile("" ::: "memory");     // compiler barrier only (no cache ops)
        }

        // ---- per-wave stage: rows gv*8..+8 of half kh (8 rows x 128 qwords) ----
        {
            const unsigned long long* hp64 = (const unsigned long long*)
                (hbuf32 + (size_t)(s & 1) * (BATCH * HID / 2)) + (size_t)grp * 32 * 256;
            unsigned long long tmp[16];
            if (use_local) {
                #pragma unroll
                for (int it = 0; it < 16; ++it) {
                    int flat = it * 64 + lane;           // 0..1023
                    int row  = gv * 8 + (flat >> 7);
                    int colq = kh * 128 + (flat & 127);
                    tmp[it] = __hip_atomic_load(&hp64[row * 256 + colq],
                                                __ATOMIC_RELAXED, __HIP_MEMORY_SCOPE_AGENT);
                }
            } else {
                #pragma unroll
                for (int it = 0; it < 16; ++it) {
                    int flat = it * 64 + lane;
                    int row  = gv * 8 + (flat >> 7);
                    int colq = kh * 128 + (flat & 127);
                    tmp[it] = __hip_atomic_load(&hp64[row * 256 + colq],
                                                __ATOMIC_RELAXED, __HIP_MEMORY_SCOPE_SYSTEM);
                }
            }
            #pragma unroll
            for (int it = 0; it < 16; ++it) {
                int flat = it * 64 + lane;
                int row  = gv * 8 + (flat >> 7);
                int colq = kh * 128 + (flat & 127);
                hs64[row * 258 + colq] = tmp[it];
            }
            if (lane == 0) {
                // drain this wave's ds_writes, then bump the half counter.
                // workgroup-scope release: s_waitcnt only, NO cache maintenance.
                __builtin_amdgcn_fence(__ATOMIC_RELEASE, "workgroup");
                __hip_atomic_fetch_add(&scnt[kh], 1, __ATOMIC_RELAXED,
                                       __HIP_MEMORY_SCOPE_WORKGROUP);
            }
        }
        // ---- wait for my half fully staged (4 waves, monotone target) ----
        {
            const int starget = 4 * (s + 1);
            for (;;) {
                int v = __hip_atomic_load(&scnt[kh], __ATOMIC_RELAXED,
                                          __HIP_MEMORY_SCOPE_WORKGROUP);
                if (v >= starget) break;
                __builtin_amdgcn_s_sleep(1);
            }
            __builtin_amdgcn_fence(__ATOMIC_ACQUIRE, "workgroup");   // s_waitcnt only
        }

        // ---- GEMM: 32x32 tile for gate gv over K-half kh, B from registers ----
        floatx16 acc = {0.f,0.f,0.f,0.f,0.f,0.f,0.f,0.f,0.f,0.f,0.f,0.f,0.f,0.f,0.f,0.f};
        const unsigned short* ap = hs + m32 * 1032 + kh * 512 + hv5 * 8;
        #pragma unroll
        for (int i = 0; i < 32; ++i) {
            bf16x8 a = *(const bf16x8*)(ap + i * 16);
            acc = __builtin_amdgcn_mfma_f32_32x32x16_bf16(a, Bf[i], acc, 0, 0, 0);
        }

        // ---- scatter C (col=lane&31, row=(reg&3)+8*(reg>>2)+4*(lane>>5)) ----
        {
            float* gb = &gbuf[(size_t)(gv * 2 + kh) * 32 * 36];
            #pragma unroll
            for (int reg = 0; reg < 16; ++reg) {
                int row = (reg & 3) + 8 * (reg >> 2) + 4 * hv5;
                gb[row * 36 + m32] = acc[reg];
            }
        }
        __syncthreads();                       // barrier b: gbuf complete

        // ---- elementwise LSTM cell update, h(s+1) out ----
        {
            int tk = xtok[erow * 512 + s];
            const float* xb = &xwl[tk * 128];
            const int go = erow * 36 + jc2 * 2;
            floatx2 ag = *(const floatx2*)&gbuf[0 * 32 * 36 + go]
                       + *(const floatx2*)&gbuf[1 * 32 * 36 + go];
            floatx2 ai = *(const floatx2*)&gbuf[2 * 32 * 36 + go]
                       + *(const floatx2*)&gbuf[3 * 32 * 36 + go];
            floatx2 af = *(const floatx2*)&gbuf[4 * 32 * 36 + go]
                       + *(const floatx2*)&gbuf[5 * 32 * 36 + go];
            floatx2 ao = *(const floatx2*)&gbuf[6 * 32 * 36 + go]
                       + *(const floatx2*)&gbuf[7 * 32 * 36 + go];
            floatx2 xg = *(const floatx2*)&xb[0 * 32 + jc2 * 2];
            floatx2 xi = *(const floatx2*)&xb[1 * 32 + jc2 * 2];
            floatx2 xf = *(const floatx2*)&xb[2 * 32 + jc2 * 2];
            floatx2 xo = *(const floatx2*)&xb[3 * 32 + jc2 * 2];
            unsigned int hvv[2];
            #pragma unroll
            for (int u = 0; u < 2; ++u) {
                float g  = tanh_fast(ag[u] + xg[u]);
                float ii = sig_fast(ai[u] + xi[u]);
                float ff = sig_fast(af[u] + xf[u]);
                float oo = sig_fast(ao[u] + xo[u]);
                float cn = g * ii + cst[u] * ff;
                float h  = tanh_fast(cn) * oo;
                cst[u]   = (tk != 0) ? cn : 0.0f;   // pad = ((x+1)//2) in {0,1,1}
                hvv[u]   = f2bf(h);
            }
            unsigned int* hnext = hbuf32 + (size_t)((s + 1) & 1) * (BATCH * HID / 2);
            unsigned int* hp = &hnext[((grp * 32 + erow) * HID + w * 32 + jc2 * 2) >> 1];
            unsigned int hval = hvv[0] | (hvv[1] << 16);
            if (use_local) {
                // plain write-back store into the shared XCD L2 (no LLC RTT)
                __hip_atomic_store(hp, hval, __ATOMIC_RELAXED, __HIP_MEMORY_SCOPE_WORKGROUP);
            } else {
                __hip_atomic_store(hp, hval, __ATOMIC_RELAXED, __HIP_MEMORY_SCOPE_SYSTEM);
            }
        }

        // ---- per-wave early publish: wave-local vmcnt drain, relaxed RMW ----
        if (s < T_SEQ - 1) {
            asm volatile("s_waitcnt vmcnt(0)" ::: "memory");   // this wave's h-stores in L2/LLC
            if (lane == 0) {
                if (use_local) {
                    __hip_atomic_fetch_add(&flags[grp * 32 + w], 1, __ATOMIC_RELAXED,
                                           __HIP_MEMORY_SCOPE_WORKGROUP);
                } else {
                    __hip_atomic_fetch_add(&flags[grp * 32 + w], 1, __ATOMIC_RELAXED,
                                           __HIP_MEMORY_SCOPE_SYSTEM);
                }
            }
        }
        __syncthreads();                       // barrier d: hs/gbuf reuse ordering
    }
}

// -------------------- projection + log_softmax over batch dim ---------------
__global__ void proj_kernel(const unsigned short* __restrict__ h,
                            const float* __restrict__ wph, const float* __restrict__ bp,
                            float* __restrict__ out) {
    __shared__ float wl[HID * NCLS];
    __shared__ float red[256];
    int tid = threadIdx.x;      // = batch row
    for (int i = tid; i < HID * NCLS; i += 256) wl[i] = wph[i];
    __syncthreads();
    float p[NCLS];
    #pragma unroll
    for (int c2 = 0; c2 < NCLS; ++c2) p[c2] = bp[c2];
    const unsigned short* hr = h + tid * HID;
    for (int k0 = 0; k0 < HID / 8; ++k0) {
        bf16x8 hv = *(const bf16x8*)(hr + k0 * 8);
        #pragma unroll
        for (int j = 0; j < 8; ++j) {
            float hk = (float)hv[j];
            #pragma unroll
            for (int c2 = 0; c2 < NCLS; ++c2) p[c2] += hk * wl[(k0 * 8 + j) * NCLS + c2];
        }
    }
    for (int c2 = 0; c2 < NCLS; ++c2) {
        red[tid] = p[c2];
        __syncthreads();
        for (int s = 128; s > 0; s >>= 1) {
            if (tid < s) red[tid] = fmaxf(red[tid], red[tid + s]);
            __syncthreads();
        }
        float mx = red[0];
        __syncthreads();
        red[tid] = __expf(p[c2] - mx);
        __syncthreads();
        for (int s = 128; s > 0; s >>= 1) {
            if (tid < s) red[tid] += red[tid + s];
            __syncthreads();
        }
        float lse = mx + __logf(red[0]);
        __syncthreads();
        out[tid * NCLS + c2] = p[c2] - lse;
    }
}

// ----------------------------------------------------------------------------
extern "C" void kernel_launch(void* const* d_in, const int* in_sizes, int n_in,
                              void* d_out, int out_size, void* d_ws, size_t ws_size,
                              hipStream_t stream) {
    const int*   x    = (const int*)d_in[0];
    const float* emb  = (const float*)d_in[1];
    const float* wgx  = (const float*)d_in[2];
    const float* wgh  = (const float*)d_in[3];
    const float* bg_  = (const float*)d_in[4];
    const float* wix  = (const float*)d_in[5];
    const float* wih  = (const float*)d_in[6];
    const float* bi_  = (const float*)d_in[7];
    const float* wfx  = (const float*)d_in[8];
    const float* wfh  = (const float*)d_in[9];
    const float* bf_  = (const float*)d_in[10];
    const float* wox  = (const float*)d_in[11];
    const float* woh  = (const float*)d_in[12];
    const float* bo_  = (const float*)d_in[13];
    const float* wph  = (const float*)d_in[14];
    const float* bp_  = (const float*)d_in[15];
    float* out = (float*)d_out;

    char* wsp = (char*)d_ws;
    int*            flags = (int*)wsp;                                      // 4 KB
    int*            xflag = (int*)(wsp + 4096);                             // 4 KB
    float*          XW    = (float*)(wsp + 8192);                           // 48 KB
    unsigned short* Wt    = (unsigned short*)(wsp + 8192 + 49152);          // 8 MB
    unsigned int*   hbuf32= (unsigned int*)(wsp + 8192 + 49152 + 8388608);  // 1 MB

    hipMemsetAsync(flags, 0, 8192, stream);                                  // flags+xflag
    hipMemsetAsync(hbuf32, 0, BATCH * HID * sizeof(unsigned short), stream); // h0 = 0

    prep_xw_kernel<<<48, 256, 0, stream>>>(emb, wgx, wix, wfx, wox,
                                           bg_, bi_, bf_, bo_, XW);
    prep_w_kernel<<<8192, 64, 0, stream>>>(wgh, wih, wfh, woh, Wt);

    void* args[] = { (void*)&x, (void*)&XW, (void*)&Wt, (void*)&hbuf32,
                     (void*)&flags, (void*)&xflag };
    hipError_t cerr = hipLaunchCooperativeKernel((void*)lstm_kernel, dim3(256), dim3(512),
                                                 args, 0, stream);
    if (cerr != hipSuccess) {
        // Fallback: plain launch. The flag protocol needs only co-residency,
        // which grid=256 at 1 WG/CU provides.
        lstm_kernel<<<dim3(256), dim3(512), 0, stream>>>(x, XW, Wt, hbuf32, flags, xflag);
    }

    proj_kernel<<<1, 256, 0, stream>>>((const unsigned short*)hbuf32, wph, bp_, out);
}

// Round 6
// 1798.512 us; speedup vs baseline: 12.2780x; 1.8349x over previous
//
#include <hip/hip_runtime.h>
#include <hip/hip_bf16.h>

#define T_SEQ 512
#define BATCH 256
#define HID   1024
#define EMBD  256
#define NCLS  10

typedef __bf16 bf16x8 __attribute__((ext_vector_type(8)));
typedef float  floatx16 __attribute__((ext_vector_type(16)));
typedef float  floatx2 __attribute__((ext_vector_type(2)));
typedef unsigned short ushortx8 __attribute__((ext_vector_type(8)));

__device__ __forceinline__ unsigned int f2bf(float f) {
    unsigned int u = __builtin_bit_cast(unsigned int, f);
    u += 0x7fffu + ((u >> 16) & 1u);
    return u >> 16;
}
__device__ __forceinline__ float sig_fast(float x) {
    return __builtin_amdgcn_rcpf(1.0f + __expf(-x));
}
__device__ __forceinline__ float tanh_fast(float x) {
    return 1.0f - 2.0f * __builtin_amdgcn_rcpf(1.0f + __expf(2.0f * x));
}

// -------------------- prep: XW[tok][gate][n] = emb[tok] @ Wx_gate + b_gate ---
__global__ void prep_xw_kernel(const float* __restrict__ emb,
                               const float* __restrict__ wgx, const float* __restrict__ wix,
                               const float* __restrict__ wfx, const float* __restrict__ wox,
                               const float* __restrict__ bg,  const float* __restrict__ bi,
                               const float* __restrict__ bf,  const float* __restrict__ bo,
                               float* __restrict__ XW) {
    int gid = blockIdx.x * blockDim.x + threadIdx.x;     // 3*4*1024 = 12288
    if (gid >= 3 * 4 * HID) return;
    int tok  = gid >> 12;
    int gate = (gid >> 10) & 3;
    int n    = gid & 1023;
    const float* W = gate == 0 ? wgx : gate == 1 ? wix : gate == 2 ? wfx : wox;
    const float* B = gate == 0 ? bg  : gate == 1 ? bi  : gate == 2 ? bf  : bo;
    float acc = B[n];
    const float* e = emb + tok * EMBD;
    for (int k = 0; k < EMBD; ++k) acc += e[k] * W[k * HID + n];
    XW[gid] = acc;
}

// ---- prep: Wt in 32x32x16 MFMA B-fragment order (R0 layout) ----
// frag = ((w*4+g)*2+kh)*32 + i ; Wt[frag*512 + lane*8 + e]
//   = bf16( W_g[k = kh*512 + i*16 + (lane>>5)*8 + e][j = w*32 + (lane&31)] )
__global__ void prep_w_kernel(const float* __restrict__ wgh, const float* __restrict__ wih,
                              const float* __restrict__ wfh, const float* __restrict__ woh,
                              unsigned short* __restrict__ Wt) {
    int bid = blockIdx.x;                 // 8192 = g(4) x kh(2) x i(32) x w(32)
    int w   = bid & 31;
    int i   = (bid >> 5) & 31;
    int kh  = (bid >> 10) & 1;
    int g   = bid >> 11;
    const float* W = g == 0 ? wgh : g == 1 ? wih : g == 2 ? wfh : woh;
    int lane = threadIdx.x;               // 64
    int j    = w * 32 + (lane & 31);
    int k0   = kh * 512 + i * 16 + (lane >> 5) * 8;
    ushortx8 o8;
    #pragma unroll
    for (int e = 0; e < 8; ++e) o8[e] = (unsigned short)f2bf(W[(k0 + e) * HID + j]);
    int frag = ((w * 4 + g) * 2 + kh) * 32 + i;
    *(ushortx8*)&Wt[frag * 512 + lane * 8] = o8;
}

// -------------------- persistent recurrent kernel ---------------------------
// 256 WGs x 512 threads. grp = blockIdx%8 owns 32 batch rows; w = blockIdx/8
// owns 32 hidden cols. Wave wv: gate gv = wv>>1, K-half kh = wv&1 (R0-proven
// structure: 8 partial tiles, 2-term GSUM, single acc).
//
// R12 = R0 + ONE change: wave-specialized split staging so the h-stage
// overlaps the GEMM within a step.
//  - phase 1: ALL 8 waves stage half 0 (32 rows x 128 qwords, 8 qwords/thr),
//    drain, bump LDS counter scnt[0] (workgroup release = s_waitcnt only).
//  - kh0 waves: wait scnt[0] == 8*(s+1) (LDS tight poll, workgroup acquire),
//    then run their 128 MFMAs on half 0.
//  - kh1 waves: meanwhile stage half 1 alone (16 qwords/thr, hidden under
//    kh0's ~1033 cyc of MFMA), bump scnt[1], wait 4*(s+1), GEMM half 1.
// Global flag protocol, scatter/ew, both remaining barriers, and publish are
// BYTE-IDENTICAL to R0 (R10/R11 lessons: no agent/system fences in-loop, no
// global RMWs in-loop, single-writer plain-store flags, wave0-only spin).
__global__ __launch_bounds__(512, 2)
void lstm_kernel(const int* __restrict__ x, const float* __restrict__ XW,
                 const unsigned short* __restrict__ Wt,
                 unsigned int* __restrict__ hbuf32, int* __restrict__ flags,
                 int* __restrict__ xflag) {
    __shared__ unsigned short hs[32 * 1032];      // h stage, +8 shorts pad (66048 B)
    __shared__ float gbuf[8 * 32 * 36];           // [gate][kh][row][col+pad] (36864 B)
    __shared__ float xwl[384];                    // [tok][gate][32 cols]     (1536 B)
    __shared__ unsigned char xtok[32 * 512];      // tokens, byte-packed      (16384 B)
    __shared__ int scnt[2];                       // half-stage counters (monotone)
    __shared__ int use_local_sh;

    const int tid  = threadIdx.x;
    const int grp  = blockIdx.x & 7;
    const int w    = blockIdx.x >> 3;
    const int wv   = tid >> 6;
    const int gv   = wv >> 1;                  // gate
    const int kh   = wv & 1;                   // K-half
    const int lane = tid & 63;
    const int m32  = lane & 31;
    const int hv5  = lane >> 5;

    // ---- XCD-locality check (one-time, system-scope => placement-safe) ----
    {
        int xcc = 0;
        asm volatile("s_getreg_b32 %0, hwreg(HW_REG_XCC_ID)" : "=s"(xcc));
        if (tid == 0) {
            __hip_atomic_store(&xflag[grp * 32 + w], xcc + 1, __ATOMIC_RELAXED,
                               __HIP_MEMORY_SCOPE_SYSTEM);
        }
        if (wv == 0) {
            int v;
            for (;;) {
                v = __hip_atomic_load(&xflag[grp * 32 + (lane & 31)], __ATOMIC_RELAXED,
                                      __HIP_MEMORY_SCOPE_SYSTEM);
                if (__all(v != 0)) break;
                __builtin_amdgcn_s_sleep(2);
            }
            int v0 = __shfl(v, 0, 64);
            if (lane == 0) use_local_sh = __all(v == v0) ? 1 : 0;
        }
    }

    // one-time: B fragments into registers (128 regs/lane, AGPR-backed)
    bf16x8 Bf[32];
    {
        const unsigned short* wb = Wt + (size_t)(((w * 4 + gv) * 2 + kh) * 32) * 512
                                      + (size_t)lane * 8;
        #pragma unroll
        for (int i = 0; i < 32; ++i)
            Bf[i] = *(const bf16x8*)(wb + i * 512);
    }
    // one-time: XW slice into LDS
    if (tid < 384) {
        int tok = tid >> 7, g = (tid >> 5) & 3, jl = tid & 31;
        xwl[tid] = XW[(tok * 4 + g) * HID + w * 32 + jl];
    }
    if (tid < 2) scnt[tid] = 0;
    // one-time: token table into LDS (byte-packed)
    #pragma unroll
    for (int it = 0; it < 32; ++it) {
        int flat = it * 512 + tid;                 // 16384 tokens
        int row  = flat >> 9;
        int col  = flat & 511;
        xtok[flat] = (unsigned char)x[(grp * 32 + row) * T_SEQ + col];
    }
    __syncthreads();
    const bool use_local = (use_local_sh != 0);

    // elementwise ownership: thread -> row = tid>>4, cols jc2*2..+2
    const int erow = tid >> 4;
    const int jc2  = tid & 15;
    float cst[2] = {0.f, 0.f};
    unsigned long long* hs64 = (unsigned long long*)hs;

    for (int s = 0; s < T_SEQ; ++s) {
        // ---- wait for h(s) from all 32 group members (R0 protocol) ----
        if (s > 0) {
            if (wv == 0) {
                const int fidx = grp * 32 + (lane & 31);
                if (use_local) {
                    while (__hip_atomic_load(&flags[fidx], __ATOMIC_RELAXED,
                                             __HIP_MEMORY_SCOPE_AGENT) < s)
                        __builtin_amdgcn_s_sleep(1);
                } else {
                    while (__hip_atomic_load(&flags[fidx], __ATOMIC_RELAXED,
                                             __HIP_MEMORY_SCOPE_SYSTEM) < s)
                        __builtin_amdgcn_s_sleep(1);
                }
            }
            __syncthreads();
        }

        const unsigned long long* hp64 = (const unsigned long long*)
            (hbuf32 + (size_t)(s & 1) * (BATCH * HID / 2)) + (size_t)grp * 32 * 256;

        // ---- phase 1: ALL waves stage half 0 (32 rows x 128 qwords) ----
        {
            unsigned long long tmp[8];
            if (use_local) {
                #pragma unroll
                for (int it = 0; it < 8; ++it) {
                    int flat = it * 512 + tid;           // 4096 qwords
                    tmp[it] = __hip_atomic_load(&hp64[(flat >> 7) * 256 + (flat & 127)],
                                                __ATOMIC_RELAXED, __HIP_MEMORY_SCOPE_AGENT);
                }
            } else {
                #pragma unroll
                for (int it = 0; it < 8; ++it) {
                    int flat = it * 512 + tid;
                    tmp[it] = __hip_atomic_load(&hp64[(flat >> 7) * 256 + (flat & 127)],
                                                __ATOMIC_RELAXED, __HIP_MEMORY_SCOPE_SYSTEM);
                }
            }
            #pragma unroll
            for (int it = 0; it < 8; ++it) {
                int flat = it * 512 + tid;
                hs64[(flat >> 7) * 258 + (flat & 127)] = tmp[it];
            }
            __builtin_amdgcn_fence(__ATOMIC_RELEASE, "workgroup");  // lgkmcnt only
            if (lane == 0)
                __hip_atomic_fetch_add(&scnt[0], 1, __ATOMIC_RELAXED,
                                       __HIP_MEMORY_SCOPE_WORKGROUP);
        }

        if (kh == 0) {
            // ---- wait half 0 fully staged (8 wave-bumps this step) ----
            const int t0 = 8 * (s + 1);
            while (__hip_atomic_load(&scnt[0], __ATOMIC_RELAXED,
                                     __HIP_MEMORY_SCOPE_WORKGROUP) < t0) {}
            __builtin_amdgcn_fence(__ATOMIC_ACQUIRE, "workgroup");
        } else {
            // ---- phase 2: kh1 waves stage half 1 (32 rows x 128 qwords) ----
            unsigned long long tmp[16];
            const int p = ((wv >> 1) << 6) | lane;       // 0..255 over kh1 threads
            if (use_local) {
                #pragma unroll
                for (int it = 0; it < 16; ++it) {
                    int flat = it * 256 + p;             // 4096 qwords
                    tmp[it] = __hip_atomic_load(
                        &hp64[(flat >> 7) * 256 + 128 + (flat & 127)],
                        __ATOMIC_RELAXED, __HIP_MEMORY_SCOPE_AGENT);
                }
            } else {
                #pragma unroll
                for (int it = 0; it < 16; ++it) {
                    int flat = it * 256 + p;
                    tmp[it] = __hip_atomic_load(
                        &hp64[(flat >> 7) * 256 + 128 + (flat & 127)],
                        __ATOMIC_RELAXED, __HIP_MEMORY_SCOPE_SYSTEM);
                }
            }
            #pragma unroll
            for (int it = 0; it < 16; ++it) {
                int flat = it * 256 + p;
                hs64[(flat >> 7) * 258 + 128 + (flat & 127)] = tmp[it];
            }
            __builtin_amdgcn_fence(__ATOMIC_RELEASE, "workgroup");
            if (lane == 0)
                __hip_atomic_fetch_add(&scnt[1], 1, __ATOMIC_RELAXED,
                                       __HIP_MEMORY_SCOPE_WORKGROUP);
            const int t1 = 4 * (s + 1);
            while (__hip_atomic_load(&scnt[1], __ATOMIC_RELAXED,
                                     __HIP_MEMORY_SCOPE_WORKGROUP) < t1) {}
            __builtin_amdgcn_fence(__ATOMIC_ACQUIRE, "workgroup");
        }

        // ---- GEMM: 32x32 tile for gate gv over K-half kh, B from registers ----
        floatx16 acc = {0.f,0.f,0.f,0.f,0.f,0.f,0.f,0.f,0.f,0.f,0.f,0.f,0.f,0.f,0.f,0.f};
        const unsigned short* ap = hs + m32 * 1032 + kh * 512 + hv5 * 8;
        #pragma unroll
        for (int i = 0; i < 32; ++i) {
            bf16x8 a = *(const bf16x8*)(ap + i * 16);
            acc = __builtin_amdgcn_mfma_f32_32x32x16_bf16(a, Bf[i], acc, 0, 0, 0);
        }

        // ---- scatter C (col=lane&31, row=(reg&3)+8*(reg>>2)+4*(lane>>5)) ----
        {
            float* gb = &gbuf[(size_t)(gv * 2 + kh) * 32 * 36];
            #pragma unroll
            for (int reg = 0; reg < 16; ++reg) {
                int row = (reg & 3) + 8 * (reg >> 2) + 4 * hv5;
                gb[row * 36 + m32] = acc[reg];
            }
        }
        __syncthreads();

        // ---- elementwise LSTM cell update, h(s+1) out ----
        {
            int tk = xtok[erow * 512 + s];
            const float* xb = &xwl[tk * 128];
            const int go = erow * 36 + jc2 * 2;
            floatx2 ag = *(const floatx2*)&gbuf[0 * 32 * 36 + go]
                       + *(const floatx2*)&gbuf[1 * 32 * 36 + go];
            floatx2 ai = *(const floatx2*)&gbuf[2 * 32 * 36 + go]
                       + *(const floatx2*)&gbuf[3 * 32 * 36 + go];
            floatx2 af = *(const floatx2*)&gbuf[4 * 32 * 36 + go]
                       + *(const floatx2*)&gbuf[5 * 32 * 36 + go];
            floatx2 ao = *(const floatx2*)&gbuf[6 * 32 * 36 + go]
                       + *(const floatx2*)&gbuf[7 * 32 * 36 + go];
            floatx2 xg = *(const floatx2*)&xb[0 * 32 + jc2 * 2];
            floatx2 xi = *(const floatx2*)&xb[1 * 32 + jc2 * 2];
            floatx2 xf = *(const floatx2*)&xb[2 * 32 + jc2 * 2];
            floatx2 xo = *(const floatx2*)&xb[3 * 32 + jc2 * 2];
            unsigned int hvv[2];
            #pragma unroll
            for (int u = 0; u < 2; ++u) {
                float g  = tanh_fast(ag[u] + xg[u]);
                float ii = sig_fast(ai[u] + xi[u]);
                float ff = sig_fast(af[u] + xf[u]);
                float oo = sig_fast(ao[u] + xo[u]);
                float cn = g * ii + cst[u] * ff;
                float h  = tanh_fast(cn) * oo;
                cst[u]   = (tk != 0) ? cn : 0.0f;   // pad = ((x+1)//2) in {0,1,1}
                hvv[u]   = f2bf(h);
            }
            unsigned int* hnext = hbuf32 + (size_t)((s + 1) & 1) * (BATCH * HID / 2);
            unsigned int* hp = &hnext[((grp * 32 + erow) * HID + w * 32 + jc2 * 2) >> 1];
            unsigned int hval = hvv[0] | (hvv[1] << 16);
            if (use_local) {
                // plain write-back store into the shared XCD L2 (no LLC RTT)
                __hip_atomic_store(hp, hval, __ATOMIC_RELAXED, __HIP_MEMORY_SCOPE_WORKGROUP);
            } else {
                __hip_atomic_store(hp, hval, __ATOMIC_RELAXED, __HIP_MEMORY_SCOPE_SYSTEM);
            }
        }
        // syncthreads drains each wave's vmcnt before s_barrier => on exit, all
        // h stores of this WG are complete at their coherence point (L2 local /
        // LLC fallback) before the flag is published.
        __syncthreads();

        if (s < T_SEQ - 1 && tid == 0) {
            if (use_local) {
                __hip_atomic_store(&flags[grp * 32 + w], s + 1,
                                   __ATOMIC_RELAXED, __HIP_MEMORY_SCOPE_WORKGROUP);
            } else {
                __hip_atomic_store(&flags[grp * 32 + w], s + 1,
                                   __ATOMIC_RELAXED, __HIP_MEMORY_SCOPE_SYSTEM);
            }
        }
    }
}

// -------------------- projection + log_softmax over batch dim ---------------
__global__ void proj_kernel(const unsigned short* __restrict__ h,
                            const float* __restrict__ wph, const float* __restrict__ bp,
                            float* __restrict__ out) {
    __shared__ float wl[HID * NCLS];
    __shared__ float red[256];
    int tid = threadIdx.x;      // = batch row
    for (int i = tid; i < HID * NCLS; i += 256) wl[i] = wph[i];
    __syncthreads();
    float p[NCLS];
    #pragma unroll
    for (int c2 = 0; c2 < NCLS; ++c2) p[c2] = bp[c2];
    const unsigned short* hr = h + tid * HID;
    for (int k0 = 0; k0 < HID / 8; ++k0) {
        bf16x8 hv = *(const bf16x8*)(hr + k0 * 8);
        #pragma unroll
        for (int j = 0; j < 8; ++j) {
            float hk = (float)hv[j];
            #pragma unroll
            for (int c2 = 0; c2 < NCLS; ++c2) p[c2] += hk * wl[(k0 * 8 + j) * NCLS + c2];
        }
    }
    for (int c2 = 0; c2 < NCLS; ++c2) {
        red[tid] = p[c2];
        __syncthreads();
        for (int s = 128; s > 0; s >>= 1) {
            if (tid < s) red[tid] = fmaxf(red[tid], red[tid + s]);
            __syncthreads();
        }
        float mx = red[0];
        __syncthreads();
        red[tid] = __expf(p[c2] - mx);
        __syncthreads();
        for (int s = 128; s > 0; s >>= 1) {
            if (tid < s) red[tid] += red[tid + s];
            __syncthreads();
        }
        float lse = mx + __logf(red[0]);
        __syncthreads();
        out[tid * NCLS + c2] = p[c2] - lse;
    }
}

// ----------------------------------------------------------------------------
extern "C" void kernel_launch(void* const* d_in, const int* in_sizes, int n_in,
                              void* d_out, int out_size, void* d_ws, size_t ws_size,
                              hipStream_t stream) {
    const int*   x    = (const int*)d_in[0];
    const float* emb  = (const float*)d_in[1];
    const float* wgx  = (const float*)d_in[2];
    const float* wgh  = (const float*)d_in[3];
    const float* bg_  = (const float*)d_in[4];
    const float* wix  = (const float*)d_in[5];
    const float* wih  = (const float*)d_in[6];
    const float* bi_  = (const float*)d_in[7];
    const float* wfx  = (const float*)d_in[8];
    const float* wfh  = (const float*)d_in[9];
    const float* bf_  = (const float*)d_in[10];
    const float* wox  = (const float*)d_in[11];
    const float* woh  = (const float*)d_in[12];
    const float* bo_  = (const float*)d_in[13];
    const float* wph  = (const float*)d_in[14];
    const float* bp_  = (const float*)d_in[15];
    float* out = (float*)d_out;

    char* wsp = (char*)d_ws;
    int*            flags = (int*)wsp;                                      // 4 KB
    int*            xflag = (int*)(wsp + 4096);                             // 4 KB
    float*          XW    = (float*)(wsp + 8192);                           // 48 KB
    unsigned short* Wt    = (unsigned short*)(wsp + 8192 + 49152);          // 8 MB
    unsigned int*   hbuf32= (unsigned int*)(wsp + 8192 + 49152 + 8388608);  // 1 MB

    hipMemsetAsync(flags, 0, 8192, stream);                                  // flags+xflag
    hipMemsetAsync(hbuf32, 0, BATCH * HID * sizeof(unsigned short), stream); // h0 = 0

    prep_xw_kernel<<<48, 256, 0, stream>>>(emb, wgx, wix, wfx, wox,
                                           bg_, bi_, bf_, bo_, XW);
    prep_w_kernel<<<8192, 64, 0, stream>>>(wgh, wih, wfh, woh, Wt);

    void* args[] = { (void*)&x, (void*)&XW, (void*)&Wt, (void*)&hbuf32,
                     (void*)&flags, (void*)&xflag };
    hipError_t cerr = hipLaunchCooperativeKernel((void*)lstm_kernel, dim3(256), dim3(512),
                                                 args, 0, stream);
    if (cerr != hipSuccess) {
        // Fallback: plain launch. The flag protocol needs only co-residency,
        // which grid=256 at 1 WG/CU provides.
        lstm_kernel<<<dim3(256), dim3(512), 0, stream>>>(x, XW, Wt, hbuf32, flags, xflag);
    }

    proj_kernel<<<1, 256, 0, stream>>>((const unsigned short*)hbuf32, wph, bp_, out);
}